// Round 1
// baseline (413.657 us; speedup 1.0000x reference)
//
#include <hip/hip_runtime.h>
#include <hip/hip_bf16.h>
#include <math.h>

// Problem: B=32, L=2048, E=512, Q=512, K=E+Q=1024, M=B*L=65536
// out = [applied (32*512 f32), weights (32*2048 f32)]

typedef __attribute__((ext_vector_type(8))) short bf16x8;
typedef __attribute__((ext_vector_type(4))) float f32x4;

#define BDIM 32
#define LDIM 2048
#define EDIM 512
#define QDIM 512
#define KDIM 1024
#define MDIM (BDIM * LDIM)

#define BM 128
#define BN 128
#define BK 64
#define LDS_STRIDE (BK + 8) // 72 bf16 = 144B rows: breaks power-of-2 bank stride

__device__ inline unsigned short f2bf(float x) {
    unsigned int u = __builtin_bit_cast(unsigned int, x);
    u += 0x7FFF + ((u >> 16) & 1); // round-to-nearest-even
    return (unsigned short)(u >> 16);
}

__global__ __launch_bounds__(256) void scores_kernel(
    const float* __restrict__ emb, const float* __restrict__ query,
    const float* __restrict__ W, const float* __restrict__ b_attn,
    const float* __restrict__ v_w, float* __restrict__ scores)
{
    __shared__ unsigned short As[BM][LDS_STRIDE];
    __shared__ unsigned short Bs[BN][LDS_STRIDE];

    const int tid = threadIdx.x;
    const int bid = blockIdx.x;
    const int mtile = bid >> 2;   // n fastest -> 4 consecutive blocks share A-tile (L3 reuse)
    const int ntile = bid & 3;
    const int m0 = mtile * BM;
    const int n0 = ntile * BN;

    const int lane = tid & 63;
    const int wv = tid >> 6;          // 4 waves
    const int wm = (wv >> 1) * 64;    // wave's 64x64 quadrant
    const int wn = (wv & 1) * 64;
    const int quad = lane >> 4;
    const int ln = lane & 15;

    const int row16 = tid >> 4;       // staging: 16 rows/pass, 16 float4 cols
    const int col4  = (tid & 15) * 4;

    f32x4 acc[4][4];
    #pragma unroll
    for (int i = 0; i < 4; i++)
        #pragma unroll
        for (int j = 0; j < 4; j++)
            acc[i][j] = (f32x4){0.f, 0.f, 0.f, 0.f};

    for (int k0 = 0; k0 < KDIM; k0 += BK) {
        // ---- stage A (cat = [query | emb], query first) as bf16 ----
        const float* asrc = (k0 < QDIM) ? query : emb;
        const int koff = (k0 < QDIM) ? k0 : (k0 - QDIM);
        #pragma unroll
        for (int p = 0; p < 8; p++) {
            const int r = p * 16 + row16;
            const float4 v = *(const float4*)(asrc + (size_t)(m0 + r) * 512 + koff + col4);
            ushort4 pk;
            pk.x = f2bf(v.x); pk.y = f2bf(v.y); pk.z = f2bf(v.z); pk.w = f2bf(v.w);
            *(ushort4*)&As[r][col4] = pk;
        }
        // ---- stage W rows (W is N x K row-major = B^T layout) ----
        #pragma unroll
        for (int p = 0; p < 8; p++) {
            const int r = p * 16 + row16;
            const float4 v = *(const float4*)(W + (size_t)(n0 + r) * 1024 + k0 + col4);
            ushort4 pk;
            pk.x = f2bf(v.x); pk.y = f2bf(v.y); pk.z = f2bf(v.z); pk.w = f2bf(v.w);
            *(ushort4*)&Bs[r][col4] = pk;
        }
        __syncthreads();

        #pragma unroll
        for (int ks = 0; ks < 2; ks++) {
            bf16x8 af[4], bf[4];
            #pragma unroll
            for (int i = 0; i < 4; i++)
                af[i] = *(const bf16x8*)&As[wm + i * 16 + ln][ks * 32 + quad * 8];
            #pragma unroll
            for (int j = 0; j < 4; j++)
                bf[j] = *(const bf16x8*)&Bs[wn + j * 16 + ln][ks * 32 + quad * 8];
            #pragma unroll
            for (int i = 0; i < 4; i++)
                #pragma unroll
                for (int j = 0; j < 4; j++)
                    acc[i][j] = __builtin_amdgcn_mfma_f32_16x16x32_bf16(af[i], bf[j], acc[i][j], 0, 0, 0);
        }
        __syncthreads();
    }

    // ---- fused epilogue: sum_n tanh(x + b[n]) * v_w[n], reduce over 16 cols ----
    float bj[4], vj[4];
    #pragma unroll
    for (int j = 0; j < 4; j++) {
        const int n = n0 + wn + j * 16 + ln;
        bj[j] = b_attn[n];
        vj[j] = v_w[n];
    }
    #pragma unroll
    for (int i = 0; i < 4; i++) {
        #pragma unroll
        for (int r = 0; r < 4; r++) {
            float s = 0.f;
            #pragma unroll
            for (int j = 0; j < 4; j++)
                s += tanhf(acc[i][j][r] + bj[j]) * vj[j];
            #pragma unroll
            for (int off = 1; off < 16; off <<= 1)
                s += __shfl_xor(s, off, 64);
            if (ln == 0)
                atomicAdd(&scores[m0 + wm + i * 16 + quad * 4 + r], s);
        }
    }
}

__global__ __launch_bounds__(256) void softmax_apply_kernel(
    const float* __restrict__ emb, const float* __restrict__ scores,
    float* __restrict__ out_applied, float* __restrict__ out_weights)
{
    const int b = blockIdx.x >> 4;      // 16 L-chunks of 128
    const int chunk = blockIdx.x & 15;
    const int l0 = chunk * 128;
    const int tid = threadIdx.x;
    const float* srow = scores + b * LDIM;

    __shared__ float red[4];
    __shared__ float wls[128];

    // redundant-but-deterministic softmax stats over full row (8 KB, L2-hot)
    float mx = -1e30f;
    #pragma unroll
    for (int t = 0; t < 8; t++) mx = fmaxf(mx, srow[tid + t * 256]);
    #pragma unroll
    for (int off = 1; off < 64; off <<= 1) mx = fmaxf(mx, __shfl_xor(mx, off, 64));
    if ((tid & 63) == 0) red[tid >> 6] = mx;
    __syncthreads();
    mx = fmaxf(fmaxf(red[0], red[1]), fmaxf(red[2], red[3]));

    float sm = 0.f;
    #pragma unroll
    for (int t = 0; t < 8; t++) sm += expf(srow[tid + t * 256] - mx);
    #pragma unroll
    for (int off = 1; off < 64; off <<= 1) sm += __shfl_xor(sm, off, 64);
    __syncthreads();
    if ((tid & 63) == 0) red[tid >> 6] = sm;
    __syncthreads();
    sm = red[0] + red[1] + red[2] + red[3];
    const float inv = 1.f / sm;

    if (tid < 128) {
        const float w = expf(srow[l0 + tid] - mx) * inv;
        wls[tid] = w;
        out_weights[(size_t)b * LDIM + l0 + tid] = w;
    }
    __syncthreads();

    // weighted sum of embeddings (fp32, coalesced float2)
    float2 acc = {0.f, 0.f};
    const float2* erow = (const float2*)(emb + ((size_t)b * LDIM + l0) * EDIM);
    for (int l = 0; l < 128; l++) {
        const float2 v = erow[(size_t)l * 256 + tid];
        const float w = wls[l];
        acc.x += w * v.x;
        acc.y += w * v.y;
    }
    atomicAdd(&out_applied[b * EDIM + 2 * tid], acc.x);
    atomicAdd(&out_applied[b * EDIM + 2 * tid + 1], acc.y);
}

extern "C" void kernel_launch(void* const* d_in, const int* in_sizes, int n_in,
                              void* d_out, int out_size, void* d_ws, size_t ws_size,
                              hipStream_t stream) {
    const float* emb    = (const float*)d_in[0];
    const float* query  = (const float*)d_in[1];
    const float* W      = (const float*)d_in[2];
    const float* b_attn = (const float*)d_in[3];
    const float* v_w    = (const float*)d_in[4];

    float* out     = (float*)d_out;
    float* applied = out;                 // 32*512 floats
    float* weights = out + BDIM * EDIM;   // 32*2048 floats
    float* scores  = (float*)d_ws;        // 65536 floats = 256 KB scratch

    hipMemsetAsync(scores, 0, (size_t)MDIM * sizeof(float), stream);
    hipMemsetAsync(applied, 0, (size_t)BDIM * EDIM * sizeof(float), stream);

    // grid = (M/BM) * (N/BN) = 512 * 4 = 2048 blocks
    scores_kernel<<<2048, 256, 0, stream>>>(emb, query, W, b_attn, v_w, scores);

    // grid = B * 16 chunks = 512 blocks
    softmax_apply_kernel<<<512, 256, 0, stream>>>(emb, scores, applied, weights);
}

// Round 2
// 406.215 us; speedup vs baseline: 1.0183x; 1.0183x over previous
//
#include <hip/hip_runtime.h>
#include <hip/hip_bf16.h>
#include <math.h>

// Problem: B=32, L=2048, E=512, Q=512, K=E+Q=1024, M=B*L=65536
// out = [applied (32*512 f32), weights (32*2048 f32)]

typedef __attribute__((ext_vector_type(8))) short bf16x8;
typedef __attribute__((ext_vector_type(4))) float f32x4;

#define BDIM 32
#define LDIM 2048
#define EDIM 512
#define QDIM 512
#define KDIM 1024
#define MDIM (BDIM * LDIM)

#define BM 128
#define BN 128
#define BK 64
#define LDS_STRIDE (BK + 8) // 72 bf16 = 144B rows

// pack two fp32 -> two bf16 (round-half-up == RNE except exact ties; ties have
// prob ~2^-16 on random data). 2 v_add + 1 v_perm per 2 elements.
__device__ inline unsigned int pack2bf(float lo, float hi) {
    unsigned int a = __builtin_bit_cast(unsigned int, lo) + 0x8000u;
    unsigned int b = __builtin_bit_cast(unsigned int, hi) + 0x8000u;
    // dest bytes [0,1]=a[2,3], [2,3]=b[2,3]  (idx 0-3 = 2nd arg, 4-7 = 1st arg)
    return __builtin_amdgcn_perm(b, a, 0x07060302);
}

__global__ __launch_bounds__(256) void scores_kernel(
    const float* __restrict__ emb, const float* __restrict__ query,
    const float* __restrict__ W, const float* __restrict__ b_attn,
    const float* __restrict__ v_w, float* __restrict__ scores)
{
    __shared__ unsigned short As[BM][LDS_STRIDE];
    __shared__ unsigned short Bs[BN][LDS_STRIDE];

    const int tid = threadIdx.x;
    const int bid = blockIdx.x;
    // XCD-aware: blocks land on XCD (bid % 8). Give each XCD whole mtile
    // groups so the 4 ntile-sharers of one A-tile hit the same 4MB L2.
    const int xcd = bid & 7;
    const int slot = bid >> 3;            // 0..255 per XCD, in dispatch order
    const int mtile = xcd * 64 + (slot >> 2);
    const int ntile = slot & 3;
    const int m0 = mtile * BM;
    const int n0 = ntile * BN;

    const int lane = tid & 63;
    const int wv = tid >> 6;          // 4 waves
    const int wm = (wv >> 1) * 64;    // wave's 64x64 quadrant
    const int wn = (wv & 1) * 64;
    const int quad = lane >> 4;
    const int ln = lane & 15;

    const int row16 = tid >> 4;       // staging: 16 rows/pass, 16 float4 cols
    const int col4  = (tid & 15) * 4;

    f32x4 acc[4][4];
    #pragma unroll
    for (int i = 0; i < 4; i++)
        #pragma unroll
        for (int j = 0; j < 4; j++)
            acc[i][j] = (f32x4){0.f, 0.f, 0.f, 0.f};

    for (int k0 = 0; k0 < KDIM; k0 += BK) {
        // ---- stage A (cat = [query | emb], query first) as bf16 ----
        const float* asrc = (k0 < QDIM) ? query : emb;
        const int koff = (k0 < QDIM) ? k0 : (k0 - QDIM);
        #pragma unroll
        for (int p = 0; p < 8; p++) {
            const int r = p * 16 + row16;
            const float4 v = *(const float4*)(asrc + (size_t)(m0 + r) * 512 + koff + col4);
            uint2 pk;
            pk.x = pack2bf(v.x, v.y);
            pk.y = pack2bf(v.z, v.w);
            *(uint2*)&As[r][col4] = pk;
        }
        // ---- stage W rows (W is N x K row-major = B^T layout) ----
        #pragma unroll
        for (int p = 0; p < 8; p++) {
            const int r = p * 16 + row16;
            const float4 v = *(const float4*)(W + (size_t)(n0 + r) * 1024 + k0 + col4);
            uint2 pk;
            pk.x = pack2bf(v.x, v.y);
            pk.y = pack2bf(v.z, v.w);
            *(uint2*)&Bs[r][col4] = pk;
        }
        __syncthreads();

        #pragma unroll
        for (int ks = 0; ks < 2; ks++) {
            bf16x8 af[4], bf[4];
            #pragma unroll
            for (int i = 0; i < 4; i++)
                af[i] = *(const bf16x8*)&As[wm + i * 16 + ln][ks * 32 + quad * 8];
            #pragma unroll
            for (int j = 0; j < 4; j++)
                bf[j] = *(const bf16x8*)&Bs[wn + j * 16 + ln][ks * 32 + quad * 8];
            #pragma unroll
            for (int i = 0; i < 4; i++)
                #pragma unroll
                for (int j = 0; j < 4; j++)
                    acc[i][j] = __builtin_amdgcn_mfma_f32_16x16x32_bf16(af[i], bf[j], acc[i][j], 0, 0, 0);
        }
        __syncthreads();
    }

    // ---- fused epilogue: sum_n tanh(x + b[n]) * v_w[n], reduce over 16 cols ----
    float bj[4], vj[4];
    #pragma unroll
    for (int j = 0; j < 4; j++) {
        const int n = n0 + wn + j * 16 + ln;
        bj[j] = b_attn[n];
        vj[j] = v_w[n];
    }
    #pragma unroll
    for (int i = 0; i < 4; i++) {
        #pragma unroll
        for (int r = 0; r < 4; r++) {
            float s = 0.f;
            #pragma unroll
            for (int j = 0; j < 4; j++)
                s += tanhf(acc[i][j][r] + bj[j]) * vj[j];
            #pragma unroll
            for (int off = 1; off < 16; off <<= 1)
                s += __shfl_xor(s, off, 64);
            if (ln == 0)
                atomicAdd(&scores[m0 + wm + i * 16 + quad * 4 + r], s);
        }
    }
}

__global__ __launch_bounds__(256) void softmax_apply_kernel(
    const float* __restrict__ emb, const float* __restrict__ scores,
    float* __restrict__ out_applied, float* __restrict__ out_weights)
{
    const int b = blockIdx.x >> 5;      // 32 L-chunks of 64 rows
    const int chunk = blockIdx.x & 31;
    const int l0 = chunk * 64;
    const int tid = threadIdx.x;
    const float* srow = scores + b * LDIM;

    __shared__ float red[4];
    __shared__ float wls[64];
    __shared__ float partial[128 * 4];

    // redundant-but-deterministic softmax stats over full row (8 KB, L2-hot)
    float mx = -1e30f;
    #pragma unroll
    for (int t = 0; t < 8; t++) mx = fmaxf(mx, srow[tid + t * 256]);
    #pragma unroll
    for (int off = 1; off < 64; off <<= 1) mx = fmaxf(mx, __shfl_xor(mx, off, 64));
    if ((tid & 63) == 0) red[tid >> 6] = mx;
    __syncthreads();
    mx = fmaxf(fmaxf(red[0], red[1]), fmaxf(red[2], red[3]));

    float sm = 0.f;
    #pragma unroll
    for (int t = 0; t < 8; t++) sm += expf(srow[tid + t * 256] - mx);
    #pragma unroll
    for (int off = 1; off < 64; off <<= 1) sm += __shfl_xor(sm, off, 64);
    __syncthreads();
    if ((tid & 63) == 0) red[tid >> 6] = sm;
    __syncthreads();
    sm = red[0] + red[1] + red[2] + red[3];
    const float inv = 1.f / sm;

    if (tid < 64) {
        const float w = expf(srow[l0 + tid] - mx) * inv;
        wls[tid] = w;
        out_weights[(size_t)b * LDIM + l0 + tid] = w;
    }
    __syncthreads();

    // weighted sum over 64 rows: two row-halves (waves 0-1 / 2-3) each do 32
    // strided rows with float4 loads, then LDS cross-half reduce + atomics.
    const int half = tid >> 7;          // wave-uniform
    const int cg = tid & 127;           // column group of 4 floats
    float4 acc = {0.f, 0.f, 0.f, 0.f};
    const float* ebase = emb + ((size_t)b * LDIM + l0 + half) * EDIM + cg * 4;
    #pragma unroll 8
    for (int i = 0; i < 32; i++) {
        const float4 v = *(const float4*)(ebase + (size_t)2 * i * EDIM);
        const float w = wls[half + 2 * i];
        acc.x += w * v.x;
        acc.y += w * v.y;
        acc.z += w * v.z;
        acc.w += w * v.w;
    }
    if (half == 1) *(float4*)&partial[cg * 4] = acc;
    __syncthreads();
    if (half == 0) {
        const float4 p = *(const float4*)&partial[cg * 4];
        float* dst = out_applied + b * EDIM + cg * 4;
        atomicAdd(dst + 0, acc.x + p.x);
        atomicAdd(dst + 1, acc.y + p.y);
        atomicAdd(dst + 2, acc.z + p.z);
        atomicAdd(dst + 3, acc.w + p.w);
    }
}

extern "C" void kernel_launch(void* const* d_in, const int* in_sizes, int n_in,
                              void* d_out, int out_size, void* d_ws, size_t ws_size,
                              hipStream_t stream) {
    const float* emb    = (const float*)d_in[0];
    const float* query  = (const float*)d_in[1];
    const float* W      = (const float*)d_in[2];
    const float* b_attn = (const float*)d_in[3];
    const float* v_w    = (const float*)d_in[4];

    float* out     = (float*)d_out;
    float* applied = out;                 // 32*512 floats
    float* weights = out + BDIM * EDIM;   // 32*2048 floats
    float* scores  = (float*)d_ws;        // 65536 floats = 256 KB scratch

    hipMemsetAsync(scores, 0, (size_t)MDIM * sizeof(float), stream);
    hipMemsetAsync(applied, 0, (size_t)BDIM * EDIM * sizeof(float), stream);

    // grid = (M/BM) * (N/BN) = 512 * 4 = 2048 blocks
    scores_kernel<<<2048, 256, 0, stream>>>(emb, query, W, b_attn, v_w, scores);

    // grid = B * 32 chunks = 1024 blocks
    softmax_apply_kernel<<<1024, 256, 0, stream>>>(emb, scores, applied, weights);
}